// Round 1
// baseline (19706.815 us; speedup 1.0000x reference)
//
#include <hip/hip_runtime.h>
#include <math.h>

// Problem constants
#define Z_C    256
#define Z_HW   1024          // H*W = 32*32
#define N_ROWS 16384         // B*H*W
#define K_CB   8192
#define RB     128           // rows per block (main kernel)
#define KT     128           // k-tile within a k-group
#define KG     1024          // k range per block
#define NKG    8             // K_CB / KG  (also k-tiles per group)
#define CSTR   36            // LDS row stride (32 c-chunk + 4 pad): bank-safe

// workspace layout (in 4-byte elements)
#define WS_NRM  0                       // 8192 floats
#define WS_PMIN 8192                    // 16384*8 floats
#define WS_PIDX (8192 + 131072)         // 16384*8 ints
#define WS_IDX  (8192 + 262144)         // 16384 ints
#define WS_HIST (WS_IDX + 16384)        // 8192 ints
#define WS_LOSS (WS_HIST + 8192)        // 1 float

// ---------------- codebook row norms ----------------
__global__ __launch_bounds__(256) void norms_k(const float* __restrict__ cb,
                                               float* __restrict__ nrm) {
  const int wave = threadIdx.x >> 6, lane = threadIdx.x & 63;
  const int row = blockIdx.x * 4 + wave;
  const float4 v = *(const float4*)(cb + (size_t)row * Z_C + lane * 4);
  float s = v.x * v.x + v.y * v.y + v.z * v.z + v.w * v.w;
  for (int off = 32; off; off >>= 1) s += __shfl_down(s, off);
  if (lane == 0) nrm[row] = s;
}

// ---------------- main: fused distance-GEMM + argmin ----------------
// score = ||e_k||^2 - 2 z.e_k  (row-constant ||z||^2 dropped; argmin-equivalent)
__global__ __launch_bounds__(256, 3) void vq_main_k(
    const float* __restrict__ z, const float* __restrict__ cb,
    const float* __restrict__ nrm, float* __restrict__ pmin,
    int* __restrict__ pidx) {
  __shared__ float zt[RB * CSTR];   // [row][c] stride 36
  __shared__ float et[KT * CSTR];   // [k][c]   stride 36
  __shared__ float redv[RB * 16];
  __shared__ int   redi[RB * 16];

  const int tid = threadIdx.x;
  const int tx = tid & 15;          // k position
  const int ty = tid >> 4;          // row position

  const int R0 = blockIdx.y * RB;   // 128-row block never crosses a batch image
  const int bimg = R0 >> 10;
  const int hw0 = R0 & 1023;
  const float* zb = z + ((size_t)bimg * Z_C) * Z_HW + hw0; // zb[c*HW + r]

  // staging assignments
  const int s_cl = tid >> 3;            // 0..31 c-in-chunk (z staging)
  const int s_r0 = (tid & 7) << 4;      // row base 0,16,...,112
  const int e_kk = tid >> 3;            // 0..31 (codebook staging)
  const int e_cq = (tid & 7) << 2;      // c quad 0..28

  float best[8];
  int bidx[8];
#pragma unroll
  for (int i = 0; i < 8; ++i) { best[i] = 1e30f; bidx[i] = 0; }

  for (int kt = 0; kt < NKG; ++kt) {
    const int kbase = blockIdx.x * KG + kt * KT;
    float acc[8][8];
#pragma unroll
    for (int i = 0; i < 8; ++i)
#pragma unroll
      for (int j = 0; j < 8; ++j) acc[i][j] = 0.f;

    for (int cc0 = 0; cc0 < Z_C; cc0 += 32) {
      // stage z chunk (transposed gather, coalesced over hw)
      {
        const float* gz = zb + (size_t)(cc0 + s_cl) * Z_HW + s_r0;
#pragma unroll
        for (int j = 0; j < 4; ++j) {
          const float4 v = *(const float4*)(gz + 4 * j);
          const int r = s_r0 + 4 * j;
          zt[(r + 0) * CSTR + s_cl] = v.x;
          zt[(r + 1) * CSTR + s_cl] = v.y;
          zt[(r + 2) * CSTR + s_cl] = v.z;
          zt[(r + 3) * CSTR + s_cl] = v.w;
        }
      }
      // stage codebook chunk (natural layout, float4)
#pragma unroll
      for (int j = 0; j < 4; ++j) {
        const int kk = e_kk + 32 * j;
        const float4 v =
            *(const float4*)(cb + (size_t)(kbase + kk) * Z_C + cc0 + e_cq);
        *(float4*)&et[kk * CSTR + e_cq] = v;
      }
      __syncthreads();
#pragma unroll
      for (int c = 0; c < 32; c += 4) {
        float4 zv[8];
#pragma unroll
        for (int i = 0; i < 8; ++i)
          zv[i] = *(const float4*)&zt[(ty + 16 * i) * CSTR + c];
#pragma unroll
        for (int j = 0; j < 8; ++j) {
          const float4 ev = *(const float4*)&et[(tx + 16 * j) * CSTR + c];
#pragma unroll
          for (int i = 0; i < 8; ++i) {
            acc[i][j] += zv[i].x * ev.x;
            acc[i][j] += zv[i].y * ev.y;
            acc[i][j] += zv[i].z * ev.z;
            acc[i][j] += zv[i].w * ev.w;
          }
        }
      }
      __syncthreads();
    }
    // fold this k-tile into running argmin (thread-local k ascends => strict <
    // keeps first/lowest k, matching jnp.argmin tie semantics)
#pragma unroll
    for (int j = 0; j < 8; ++j) {
      const int kglob = kbase + tx + 16 * j;
      const float nk = nrm[kglob];
#pragma unroll
      for (int i = 0; i < 8; ++i) {
        const float s = nk - 2.0f * acc[i][j];
        if (s < best[i]) { best[i] = s; bidx[i] = kglob; }
      }
    }
  }
  // cross-thread reduce: 16 tx-threads own each row
#pragma unroll
  for (int i = 0; i < 8; ++i) {
    redv[(ty + 16 * i) * 16 + tx] = best[i];
    redi[(ty + 16 * i) * 16 + tx] = bidx[i];
  }
  __syncthreads();
  if (tid < RB) {
    float bv = redv[tid * 16];
    int bi = redi[tid * 16];
#pragma unroll
    for (int t = 1; t < 16; ++t) {
      const float v = redv[tid * 16 + t];
      const int ii = redi[tid * 16 + t];
      if (v < bv || (v == bv && ii < bi)) { bv = v; bi = ii; }
    }
    const int R = R0 + tid;
    pmin[(size_t)R * NKG + blockIdx.x] = bv;
    pidx[(size_t)R * NKG + blockIdx.x] = bi;
  }
}

// ---------------- reduce partial argmins across k-groups ----------------
__global__ __launch_bounds__(256) void vq_reduce_k(
    const float* __restrict__ pmin, const int* __restrict__ pidx,
    int* __restrict__ idxout, float* __restrict__ outidxf,
    int* __restrict__ hist) {
  const int r = blockIdx.x * 256 + threadIdx.x;
  float bv = pmin[(size_t)r * NKG];
  int bi = pidx[(size_t)r * NKG];
  for (int g = 1; g < NKG; ++g) {   // ascending k-ranges: strict < keeps first
    const float v = pmin[(size_t)r * NKG + g];
    const int ii = pidx[(size_t)r * NKG + g];
    if (v < bv || (v == bv && ii < bi)) { bv = v; bi = ii; }
  }
  idxout[r] = bi;
  outidxf[r] = (float)bi;
  atomicAdd(&hist[bi], 1);
}

// ---------------- gather quantized_st + loss sum ----------------
__global__ __launch_bounds__(256) void vq_gather_k(
    const float* __restrict__ z, const float* __restrict__ cb,
    const int* __restrict__ idx, float* __restrict__ out,
    float* __restrict__ loss) {
  const int e = blockIdx.x * 256 + threadIdx.x;  // [b][c][hw] flat
  const int hw = e & 1023;
  const int bc = e >> 10;
  const int c = bc & 255;
  const int bimg = bc >> 8;
  const int n = (bimg << 10) + hw;
  const int k = idx[n];
  const float zv = z[e];
  const float q = cb[(size_t)k * Z_C + c];
  const float d = q - zv;
  out[e] = zv + d;                 // z + (q - z): mirrors straight-through
  float t = d * d;                 // (z-q)^2 == (q-z)^2: loss_vq == loss_commit
  const int lane = threadIdx.x & 63, wid = threadIdx.x >> 6;
  for (int off = 32; off; off >>= 1) t += __shfl_down(t, off);
  __shared__ float ls[4];
  if (lane == 0) ls[wid] = t;
  __syncthreads();
  if (threadIdx.x == 0) atomicAdd(loss, ls[0] + ls[1] + ls[2] + ls[3]);
}

// ---------------- perplexity + losses ----------------
__global__ __launch_bounds__(256) void vq_final_k(
    const int* __restrict__ hist, const float* __restrict__ loss,
    float* __restrict__ out_tail) {
  float part = 0.f;
  for (int k = threadIdx.x; k < K_CB; k += 256) {
    const float p = (float)hist[k] * (1.0f / 16384.0f);
    part += p * logf(fmaxf(p, 1e-10f));  // p==0 -> 0*log(1e-10) == 0, matches clip
  }
  const int lane = threadIdx.x & 63, wid = threadIdx.x >> 6;
  for (int off = 32; off; off >>= 1) part += __shfl_down(part, off);
  __shared__ float ls[4];
  if (lane == 0) ls[wid] = part;
  __syncthreads();
  if (threadIdx.x == 0) {
    const float s = ls[0] + ls[1] + ls[2] + ls[3];
    out_tail[0] = expf(-s);                               // perplexity
    const float mean = *loss * (1.0f / 4194304.0f);
    out_tail[1] = mean;                                   // loss_vq
    out_tail[2] = mean;                                   // loss_commit
  }
}

extern "C" void kernel_launch(void* const* d_in, const int* in_sizes, int n_in,
                              void* d_out, int out_size, void* d_ws,
                              size_t ws_size, hipStream_t stream) {
  const float* z = (const float*)d_in[0];
  const float* cb = (const float*)d_in[1];
  float* out = (float*)d_out;
  float* ws = (float*)d_ws;

  float* nrm  = ws + WS_NRM;
  float* pmin = ws + WS_PMIN;
  int*   pidx = (int*)(ws + WS_PIDX);
  int*   idx  = (int*)(ws + WS_IDX);
  int*   hist = (int*)(ws + WS_HIST);
  float* loss = ws + WS_LOSS;

  // zero histogram + loss accumulator (re-poisoned to 0xAA before each launch)
  hipMemsetAsync(ws + WS_HIST, 0, (K_CB + 1) * sizeof(float), stream);

  norms_k<<<K_CB / 4, 256, 0, stream>>>(cb, nrm);
  vq_main_k<<<dim3(NKG, N_ROWS / RB), 256, 0, stream>>>(z, cb, nrm, pmin, pidx);
  vq_reduce_k<<<N_ROWS / 256, 256, 0, stream>>>(pmin, pidx, idx, out + 4194304,
                                                hist);
  vq_gather_k<<<4194304 / 256, 256, 0, stream>>>(z, cb, idx, out, loss);
  vq_final_k<<<1, 256, 0, stream>>>(hist, loss, out + 4210688);
}

// Round 2
// 1245.721 us; speedup vs baseline: 15.8196x; 15.8196x over previous
//
#include <hip/hip_runtime.h>
#include <math.h>

// Problem constants
#define Z_C    256
#define Z_HW   1024          // H*W = 32*32
#define N_ROWS 16384         // B*H*W
#define K_CB   8192
#define RB     128           // rows per block (main kernel)
#define KT     128           // k-tile within a k-group
#define KG     1024          // k range per block
#define NKG    8             // K_CB / KG  (also k-tiles per group)
#define CSTR   36            // LDS row stride (32 c-chunk + 4 pad): bank-safe

// workspace layout (in 4-byte elements)
#define WS_NRM  0                       // 8192 floats
#define WS_PMIN 8192                    // 16384*8 floats
#define WS_PIDX (8192 + 131072)         // 16384*8 ints
#define WS_IDX  (8192 + 262144)         // 16384 ints
#define WS_HIST (WS_IDX + 16384)        // 8192 ints
#define WS_LOSS (WS_HIST + 8192)        // 1 float

// ---------------- codebook row norms ----------------
__global__ __launch_bounds__(256) void norms_k(const float* __restrict__ cb,
                                               float* __restrict__ nrm) {
  const int wave = threadIdx.x >> 6, lane = threadIdx.x & 63;
  const int row = blockIdx.x * 4 + wave;
  const float4 v = *(const float4*)(cb + (size_t)row * Z_C + lane * 4);
  float s = v.x * v.x + v.y * v.y + v.z * v.z + v.w * v.w;
  for (int off = 32; off; off >>= 1) s += __shfl_down(s, off);
  if (lane == 0) nrm[row] = s;
}

// ---------------- main: fused distance-GEMM + argmin ----------------
// score = ||e_k||^2 - 2 z.e_k  (row-constant ||z||^2 dropped; argmin-equivalent)
// launch_bounds(256,2): 2 blocks/CU, VGPR cap 256 -> no acc spill (round-1
// lesson: (256,3) capped VGPRs so acc[8][8] spilled to scratch -> 38 GB/launch
// of scratch WRITE traffic, 19.7 ms).
__global__ __launch_bounds__(256, 2) void vq_main_k(
    const float* __restrict__ z, const float* __restrict__ cb,
    const float* __restrict__ nrm, float* __restrict__ pmin,
    int* __restrict__ pidx) {
  __shared__ float zt[RB * CSTR];   // [row][c] stride 36
  __shared__ float et[KT * CSTR];   // [k][c]   stride 36
  __shared__ float redv[RB * 16];
  __shared__ int   redi[RB * 16];

  const int tid = threadIdx.x;
  const int tx = tid & 15;          // k position
  const int ty = tid >> 4;          // row position

  const int R0 = blockIdx.y * RB;   // 128-row block never crosses a batch image
  const int bimg = R0 >> 10;
  const int hw0 = R0 & 1023;
  const float* zb = z + ((size_t)bimg * Z_C) * Z_HW + hw0; // zb[c*HW + r]

  // staging assignments
  const int s_cl = tid >> 3;            // 0..31 c-in-chunk (z staging)
  const int s_r0 = (tid & 7) << 4;      // row base 0,16,...,112
  const int e_kk = tid >> 3;            // 0..31 (codebook staging)
  const int e_cq = (tid & 7) << 2;      // c quad 0..28

  float best[8];
  int bidx[8];
#pragma unroll
  for (int i = 0; i < 8; ++i) { best[i] = 1e30f; bidx[i] = 0; }

  for (int kt = 0; kt < NKG; ++kt) {
    const int kbase = blockIdx.x * KG + kt * KT;
    float acc[8][8];
#pragma unroll
    for (int i = 0; i < 8; ++i)
#pragma unroll
      for (int j = 0; j < 8; ++j) acc[i][j] = 0.f;

    for (int cc0 = 0; cc0 < Z_C; cc0 += 32) {
      // stage z chunk (transposed gather)
      {
        const float* gz = zb + (size_t)(cc0 + s_cl) * Z_HW + s_r0;
#pragma unroll
        for (int j = 0; j < 4; ++j) {
          const float4 v = *(const float4*)(gz + 4 * j);
          const int r = s_r0 + 4 * j;
          zt[(r + 0) * CSTR + s_cl] = v.x;
          zt[(r + 1) * CSTR + s_cl] = v.y;
          zt[(r + 2) * CSTR + s_cl] = v.z;
          zt[(r + 3) * CSTR + s_cl] = v.w;
        }
      }
      // stage codebook chunk (natural layout, float4)
#pragma unroll
      for (int j = 0; j < 4; ++j) {
        const int kk = e_kk + 32 * j;
        const float4 v =
            *(const float4*)(cb + (size_t)(kbase + kk) * Z_C + cc0 + e_cq);
        *(float4*)&et[kk * CSTR + e_cq] = v;
      }
      __syncthreads();
      // micro-kernel: ev[8] resident (32 regs), zv streamed one row at a
      // time (4 regs) -> peak live ~125 VGPR, no spill.
#pragma unroll
      for (int c = 0; c < 32; c += 4) {
        float4 ev[8];
#pragma unroll
        for (int j = 0; j < 8; ++j)
          ev[j] = *(const float4*)&et[(tx + 16 * j) * CSTR + c];
#pragma unroll
        for (int i = 0; i < 8; ++i) {
          const float4 zv = *(const float4*)&zt[(ty + 16 * i) * CSTR + c];
#pragma unroll
          for (int j = 0; j < 8; ++j) {
            acc[i][j] += zv.x * ev[j].x;
            acc[i][j] += zv.y * ev[j].y;
            acc[i][j] += zv.z * ev[j].z;
            acc[i][j] += zv.w * ev[j].w;
          }
        }
      }
      __syncthreads();
    }
    // fold this k-tile into running argmin (thread-local k ascends => strict <
    // keeps first/lowest k, matching jnp.argmin tie semantics)
#pragma unroll
    for (int j = 0; j < 8; ++j) {
      const int kglob = kbase + tx + 16 * j;
      const float nk = nrm[kglob];
#pragma unroll
      for (int i = 0; i < 8; ++i) {
        const float s = nk - 2.0f * acc[i][j];
        if (s < best[i]) { best[i] = s; bidx[i] = kglob; }
      }
    }
  }
  // cross-thread reduce: 16 tx-threads own each row
#pragma unroll
  for (int i = 0; i < 8; ++i) {
    redv[(ty + 16 * i) * 16 + tx] = best[i];
    redi[(ty + 16 * i) * 16 + tx] = bidx[i];
  }
  __syncthreads();
  if (tid < RB) {
    float bv = redv[tid * 16];
    int bi = redi[tid * 16];
#pragma unroll
    for (int t = 1; t < 16; ++t) {
      const float v = redv[tid * 16 + t];
      const int ii = redi[tid * 16 + t];
      if (v < bv || (v == bv && ii < bi)) { bv = v; bi = ii; }
    }
    const int R = R0 + tid;
    pmin[(size_t)R * NKG + blockIdx.x] = bv;
    pidx[(size_t)R * NKG + blockIdx.x] = bi;
  }
}

// ---------------- reduce partial argmins across k-groups ----------------
__global__ __launch_bounds__(256) void vq_reduce_k(
    const float* __restrict__ pmin, const int* __restrict__ pidx,
    int* __restrict__ idxout, float* __restrict__ outidxf,
    int* __restrict__ hist) {
  const int r = blockIdx.x * 256 + threadIdx.x;
  float bv = pmin[(size_t)r * NKG];
  int bi = pidx[(size_t)r * NKG];
  for (int g = 1; g < NKG; ++g) {   // ascending k-ranges: strict < keeps first
    const float v = pmin[(size_t)r * NKG + g];
    const int ii = pidx[(size_t)r * NKG + g];
    if (v < bv || (v == bv && ii < bi)) { bv = v; bi = ii; }
  }
  idxout[r] = bi;
  outidxf[r] = (float)bi;
  atomicAdd(&hist[bi], 1);
}

// ---------------- gather quantized_st + loss sum ----------------
__global__ __launch_bounds__(256) void vq_gather_k(
    const float* __restrict__ z, const float* __restrict__ cb,
    const int* __restrict__ idx, float* __restrict__ out,
    float* __restrict__ loss) {
  const int e = blockIdx.x * 256 + threadIdx.x;  // [b][c][hw] flat
  const int hw = e & 1023;
  const int bc = e >> 10;
  const int c = bc & 255;
  const int bimg = bc >> 8;
  const int n = (bimg << 10) + hw;
  const int k = idx[n];
  const float zv = z[e];
  const float q = cb[(size_t)k * Z_C + c];
  const float d = q - zv;
  out[e] = zv + d;                 // z + (q - z): mirrors straight-through
  float t = d * d;                 // (z-q)^2 == (q-z)^2: loss_vq == loss_commit
  const int lane = threadIdx.x & 63, wid = threadIdx.x >> 6;
  for (int off = 32; off; off >>= 1) t += __shfl_down(t, off);
  __shared__ float ls[4];
  if (lane == 0) ls[wid] = t;
  __syncthreads();
  if (threadIdx.x == 0) atomicAdd(loss, ls[0] + ls[1] + ls[2] + ls[3]);
}

// ---------------- perplexity + losses ----------------
__global__ __launch_bounds__(256) void vq_final_k(
    const int* __restrict__ hist, const float* __restrict__ loss,
    float* __restrict__ out_tail) {
  float part = 0.f;
  for (int k = threadIdx.x; k < K_CB; k += 256) {
    const float p = (float)hist[k] * (1.0f / 16384.0f);
    part += p * logf(fmaxf(p, 1e-10f));  // p==0 -> 0*log(1e-10) == 0, matches clip
  }
  const int lane = threadIdx.x & 63, wid = threadIdx.x >> 6;
  for (int off = 32; off; off >>= 1) part += __shfl_down(part, off);
  __shared__ float ls[4];
  if (lane == 0) ls[wid] = part;
  __syncthreads();
  if (threadIdx.x == 0) {
    const float s = ls[0] + ls[1] + ls[2] + ls[3];
    out_tail[0] = expf(-s);                               // perplexity
    const float mean = *loss * (1.0f / 4194304.0f);
    out_tail[1] = mean;                                   // loss_vq
    out_tail[2] = mean;                                   // loss_commit
  }
}

extern "C" void kernel_launch(void* const* d_in, const int* in_sizes, int n_in,
                              void* d_out, int out_size, void* d_ws,
                              size_t ws_size, hipStream_t stream) {
  const float* z = (const float*)d_in[0];
  const float* cb = (const float*)d_in[1];
  float* out = (float*)d_out;
  float* ws = (float*)d_ws;

  float* nrm  = ws + WS_NRM;
  float* pmin = ws + WS_PMIN;
  int*   pidx = (int*)(ws + WS_PIDX);
  int*   idx  = (int*)(ws + WS_IDX);
  int*   hist = (int*)(ws + WS_HIST);
  float* loss = ws + WS_LOSS;

  // zero histogram + loss accumulator (re-poisoned to 0xAA before each launch)
  hipMemsetAsync(ws + WS_HIST, 0, (K_CB + 1) * sizeof(float), stream);

  norms_k<<<K_CB / 4, 256, 0, stream>>>(cb, nrm);
  vq_main_k<<<dim3(NKG, N_ROWS / RB), 256, 0, stream>>>(z, cb, nrm, pmin, pidx);
  vq_reduce_k<<<N_ROWS / 256, 256, 0, stream>>>(pmin, pidx, idx, out + 4194304,
                                                hist);
  vq_gather_k<<<4194304 / 256, 256, 0, stream>>>(z, cb, idx, out, loss);
  vq_final_k<<<1, 256, 0, stream>>>(hist, loss, out + 4210688);
}

// Round 3
// 734.267 us; speedup vs baseline: 26.8387x; 1.6966x over previous
//
#include <hip/hip_runtime.h>
#include <math.h>

typedef __attribute__((ext_vector_type(8))) __bf16 bf16x8;
typedef __attribute__((ext_vector_type(4))) float floatx4;

#define NROW 16384
#define KCB  8192
#define CDIM 256
#define KSPL 768            // [zh|zh|zl] . [eh|el|eh] = zh.eh + zh.el + zl.eh
#define TAU  0.05f          // gap threshold for exact-recompute guard
#define NNB  32             // KCB / 256 n-blocks

// workspace byte offsets
#define OFF_PACKED 0u                    // 16384 * 8
#define OFF_A      131072u               // 16384*768*2 = 25165824
#define OFF_B      25296896u             // 8192*768*2 = 12582912
#define OFF_NRM    37879808u             // 8192*4
#define OFF_PM1    37912576u             // 32*16384*4
#define OFF_PM2    40009728u
#define OFF_PIDX   42106880u
#define OFF_PROV   44204032u             // 16384*4
#define OFF_FIDX   44269568u             // 16384*4
#define OFF_FLAG   44335104u             // 16384*4
#define OFF_LIST   44400640u             // 16384*4
#define OFF_HIST   44466176u             // 8192*4
#define OFF_LOSS   44498944u             // 4
#define OFF_CNT    44498948u             // 4

__device__ __forceinline__ unsigned short f2bf(float f) {  // RNE fp32->bf16 bits
  unsigned u = __float_as_uint(f);
  return (unsigned short)((u + 0x7FFFu + ((u >> 16) & 1u)) >> 16);
}
__device__ __forceinline__ float bf2f(unsigned short b) {
  return __uint_as_float(((unsigned)b) << 16);
}
__device__ __forceinline__ unsigned pack2(unsigned short a, unsigned short b) {
  return (unsigned)a | ((unsigned)b << 16);
}
__device__ __forceinline__ void gld16(const void* g, void* l) {
  __builtin_amdgcn_global_load_lds(
      (const __attribute__((address_space(1))) unsigned int*)g,
      (__attribute__((address_space(3))) unsigned int*)l, 16, 0, 0);
}

// ---------- prep A: z [16,256,32,32] fp32 -> A [16384][768] bf16 ----------
__global__ __launch_bounds__(256) void prep_a_k(const float* __restrict__ z,
                                                unsigned short* __restrict__ A) {
  __shared__ float t[64][65];
  const int tid = threadIdx.x;
  const int bb = blockIdx.x >> 6;
  const int hw0 = ((blockIdx.x >> 2) & 15) * 64;
  const int c0 = (blockIdx.x & 3) * 64;
  const int cl = tid >> 2, h4 = (tid & 3) * 16;
  const float* src = z + ((size_t)(bb * 256 + c0 + cl)) * 1024 + hw0 + h4;
#pragma unroll
  for (int j = 0; j < 4; ++j) {
    const float4 v = *(const float4*)(src + 4 * j);
    t[cl][h4 + 4 * j + 0] = v.x; t[cl][h4 + 4 * j + 1] = v.y;
    t[cl][h4 + 4 * j + 2] = v.z; t[cl][h4 + 4 * j + 3] = v.w;
  }
  __syncthreads();
  const int hl = tid >> 2, cq = (tid & 3) * 16;
  const size_t n = (size_t)bb * 1024 + hw0 + hl;
  unsigned short hi[16], lo[16];
#pragma unroll
  for (int j = 0; j < 16; ++j) {
    const float f = t[cq + j][hl];
    const unsigned short h = f2bf(f);
    hi[j] = h;
    lo[j] = f2bf(f - bf2f(h));
  }
  unsigned short* dst = A + n * 768 + c0 + cq;
  uint4 h0 = {pack2(hi[0], hi[1]), pack2(hi[2], hi[3]), pack2(hi[4], hi[5]), pack2(hi[6], hi[7])};
  uint4 h1 = {pack2(hi[8], hi[9]), pack2(hi[10], hi[11]), pack2(hi[12], hi[13]), pack2(hi[14], hi[15])};
  uint4 l0 = {pack2(lo[0], lo[1]), pack2(lo[2], lo[3]), pack2(lo[4], lo[5]), pack2(lo[6], lo[7])};
  uint4 l1 = {pack2(lo[8], lo[9]), pack2(lo[10], lo[11]), pack2(lo[12], lo[13]), pack2(lo[14], lo[15])};
  *(uint4*)(dst) = h0;        *(uint4*)(dst + 8) = h1;         // zh  seg 0
  *(uint4*)(dst + 256) = h0;  *(uint4*)(dst + 264) = h1;       // zh  seg 1
  *(uint4*)(dst + 512) = l0;  *(uint4*)(dst + 520) = l1;       // zl  seg 2
}

// ---------- prep B: codebook -> B [8192][768] bf16 [eh|el|eh] + norms ----------
__global__ __launch_bounds__(256) void prep_b_k(const float* __restrict__ cb,
                                                unsigned short* __restrict__ B,
                                                float* __restrict__ nrm) {
  const int w = threadIdx.x >> 6, lane = threadIdx.x & 63;
  const int row = blockIdx.x * 4 + w;
  const float4 v = *(const float4*)(cb + (size_t)row * 256 + lane * 4);
  float s = v.x * v.x + v.y * v.y + v.z * v.z + v.w * v.w;
  float f[4] = {v.x, v.y, v.z, v.w};
  ushort4 hv, lv;
  unsigned short* hp = (unsigned short*)&hv;
  unsigned short* lp = (unsigned short*)&lv;
#pragma unroll
  for (int j = 0; j < 4; ++j) {
    const unsigned short h = f2bf(f[j]);
    hp[j] = h;
    lp[j] = f2bf(f[j] - bf2f(h));
  }
  unsigned short* dst = B + (size_t)row * 768 + lane * 4;
  *(ushort4*)(dst) = hv;          // eh
  *(ushort4*)(dst + 256) = lv;    // el
  *(ushort4*)(dst + 512) = hv;    // eh dup
  for (int off = 32; off; off >>= 1) s += __shfl_down(s, off);
  if (lane == 0) nrm[row] = s;
}

// ---------- main: bf16 MFMA distance GEMM + fused top-2 argmin ----------
// block tile 128(M) x 256(N), 4 waves side-by-side in N, wave = 8x4 tiles of
// 16x16x32. LDS octet XOR-swizzle keeps frag reads bank-uniform.
__global__ __launch_bounds__(256, 2) void vq_mfma_k(
    const unsigned short* __restrict__ A, const unsigned short* __restrict__ Bm,
    const float* __restrict__ nrm, float* __restrict__ pm1,
    float* __restrict__ pm2, int* __restrict__ pidx) {
  __shared__ unsigned short As[128 * 64];  // 16 KB
  __shared__ unsigned short Bs[256 * 64];  // 32 KB

  const int tid = threadIdx.x;
  const int mb = blockIdx.y, nb = blockIdx.x;
  const int w = tid >> 6, lane = tid & 63;
  const int quad = lane >> 4, lrow = lane & 15;

  // staging: thread t -> row sr (=t>>3), lds slot ss (=t&7); loads global
  // octet ss ^ (sr&7) so LDS layout is linear-in-lane (global_load_lds req.)
  const int sr = tid >> 3, ss = tid & 7;
  const int sq = ss ^ (sr & 7);
  const unsigned short* gA = A + (size_t)(mb * 128 + sr) * 768 + sq * 8;
  const unsigned short* gB = Bm + (size_t)(nb * 256 + sr) * 768 + sq * 8;
  unsigned short* lA = As + sr * 64 + ss * 8;
  unsigned short* lB = Bs + sr * 64 + ss * 8;

  floatx4 acc[8][4];
#pragma unroll
  for (int i = 0; i < 8; ++i)
#pragma unroll
    for (int j = 0; j < 4; ++j) acc[i][j] = (floatx4){0.f, 0.f, 0.f, 0.f};

  for (int kc = 0; kc < 12; ++kc) {
    const int ko = kc * 64;
#pragma unroll
    for (int i = 0; i < 4; ++i)
      gld16(gA + (size_t)(i * 32) * 768 + ko, lA + i * 32 * 64);
#pragma unroll
    for (int i = 0; i < 8; ++i)
      gld16(gB + (size_t)(i * 32) * 768 + ko, lB + i * 32 * 64);
    __syncthreads();
#pragma unroll
    for (int ks = 0; ks < 2; ++ks) {
      bf16x8 af[8], bf[4];
#pragma unroll
      for (int mt = 0; mt < 8; ++mt) {
        const int row = mt * 16 + lrow;
        const int slot = (ks * 4 + quad) ^ (row & 7);
        af[mt] = *(const bf16x8*)(As + row * 64 + slot * 8);
      }
#pragma unroll
      for (int nt = 0; nt < 4; ++nt) {
        const int row = w * 64 + nt * 16 + lrow;
        const int slot = (ks * 4 + quad) ^ (row & 7);
        bf[nt] = *(const bf16x8*)(Bs + row * 64 + slot * 8);
      }
#pragma unroll
      for (int mt = 0; mt < 8; ++mt)
#pragma unroll
        for (int nt = 0; nt < 4; ++nt)
          acc[mt][nt] = __builtin_amdgcn_mfma_f32_16x16x32_bf16(
              af[mt], bf[nt], acc[mt][nt], 0, 0, 0);
    }
    __syncthreads();
  }

  // ---- epilogue: score = nrm[k] - 2*dot; top-2 per row over 256 cols ----
  float nr[4];
#pragma unroll
  for (int nt = 0; nt < 4; ++nt) nr[nt] = nrm[nb * 256 + w * 64 + nt * 16 + lrow];

  float* Lm1 = (float*)As;             // overlay (As dead after loop)
  int* Li1 = (int*)(As + 2048);
  float* Lm2 = (float*)(As + 4096);
#pragma unroll
  for (int mt = 0; mt < 8; ++mt) {
#pragma unroll
    for (int p = 0; p < 4; ++p) {
      float m1 = 3e38f, m2 = 3e38f;
      int i1 = 0;
#pragma unroll
      for (int nt = 0; nt < 4; ++nt) {
        const float s = nr[nt] - 2.0f * acc[mt][nt][p];
        const int kg = nb * 256 + w * 64 + nt * 16 + lrow;
        if (s < m1) { m2 = m1; m1 = s; i1 = kg; }
        else m2 = fminf(m2, s);
      }
      for (int d = 1; d < 16; d <<= 1) {   // merge across 16 lrow lanes
        const float om1 = __shfl_xor(m1, d);
        const int oi1 = __shfl_xor(i1, d);
        const float om2 = __shfl_xor(m2, d);
        if (om1 < m1) { m2 = fminf(m1, om2); m1 = om1; i1 = oi1; }
        else          { m2 = fminf(m2, om1); }
      }
      if (lrow == 0) {
        const int rl = mt * 16 + quad * 4 + p;
        Lm1[rl * 4 + w] = m1; Li1[rl * 4 + w] = i1; Lm2[rl * 4 + w] = m2;
      }
    }
  }
  __syncthreads();
  if (tid < 128) {
    float m1 = Lm1[tid * 4], m2 = Lm2[tid * 4];
    int i1 = Li1[tid * 4];
#pragma unroll
    for (int v = 1; v < 4; ++v) {
      const float om1 = Lm1[tid * 4 + v], om2 = Lm2[tid * 4 + v];
      const int oi1 = Li1[tid * 4 + v];
      if (om1 < m1) { m2 = fminf(m1, om2); m1 = om1; i1 = oi1; }
      else          { m2 = fminf(m2, om1); }
    }
    const int r = mb * 128 + tid;
    pm1[(size_t)nb * NROW + r] = m1;
    pm2[(size_t)nb * NROW + r] = m2;
    pidx[(size_t)nb * NROW + r] = i1;
  }
}

// ---------- reduce partials; flag small-gap rows for exact recompute ----------
__global__ __launch_bounds__(256) void reduce1_k(
    const float* __restrict__ pm1, const float* __restrict__ pm2,
    const int* __restrict__ pidx, int* __restrict__ prov,
    int* __restrict__ flag, unsigned long long* __restrict__ packed,
    int* __restrict__ list, int* __restrict__ cnt) {
  const int r = blockIdx.x * 256 + threadIdx.x;
  float m1 = 3e38f, m2 = 3e38f;
  int i1 = 0;
  for (int nb = 0; nb < NNB; ++nb) {
    const float om1 = pm1[(size_t)nb * NROW + r], om2 = pm2[(size_t)nb * NROW + r];
    const int oi1 = pidx[(size_t)nb * NROW + r];
    if (om1 < m1) { m2 = fminf(m1, om2); m1 = om1; i1 = oi1; }
    else          { m2 = fminf(m2, om1); }
  }
  prov[r] = i1;
  const int fl = (m2 - m1 < TAU) ? 1 : 0;
  flag[r] = fl;
  if (fl) {
    packed[r] = 0xFFFFFFFFFFFFFFFFull;
    const int p = atomicAdd(cnt, 1);
    list[p] = r;
  }
}

// ---------- exact fp32 recompute for flagged rows ----------
__global__ __launch_bounds__(256) void cleanup_k(
    const float* __restrict__ z, const float* __restrict__ cb,
    const float* __restrict__ nrm, const int* __restrict__ list,
    const int* __restrict__ cnt, unsigned long long* __restrict__ packed) {
  __shared__ float zr[256];
  const int nf = *cnt;
  const int k = blockIdx.x * 32 + (threadIdx.x >> 3);  // 256 blocks cover 8192 k
  const int c0 = (threadIdx.x & 7) * 32;
  const float* cr = cb + (size_t)k * 256 + c0;
  const float nk = nrm[k];
  for (int f = 0; f < nf; ++f) {
    const int r = list[f];
    __syncthreads();
    zr[threadIdx.x] = z[((size_t)((r >> 10) * 256 + threadIdx.x)) * 1024 + (r & 1023)];
    __syncthreads();
    float p = 0.f;
#pragma unroll
    for (int c = 0; c < 32; c += 4) {
      const float4 v = *(const float4*)(cr + c);
      p += v.x * zr[c0 + c] + v.y * zr[c0 + c + 1] + v.z * zr[c0 + c + 2] +
           v.w * zr[c0 + c + 3];
    }
    p += __shfl_down(p, 4); p += __shfl_down(p, 2); p += __shfl_down(p, 1);
    if ((threadIdx.x & 7) == 0) {
      const float s = nk - 2.f * p;
      unsigned u = __float_as_uint(s);
      u ^= (unsigned)((int)u >> 31) | 0x80000000u;   // sortable float
      atomicMin(packed + r, ((unsigned long long)u << 32) | (unsigned)k);
    }
  }
}

// ---------- finalize indices + histogram ----------
__global__ __launch_bounds__(256) void finalize_k(
    const int* __restrict__ prov, const int* __restrict__ flag,
    const unsigned long long* __restrict__ packed, int* __restrict__ fidx,
    float* __restrict__ outf, int* __restrict__ hist) {
  const int r = blockIdx.x * 256 + threadIdx.x;
  const int idx = flag[r] ? (int)(packed[r] & 0xFFFFFFFFull) : prov[r];
  fidx[r] = idx;
  outf[r] = (float)idx;
  atomicAdd(&hist[idx], 1);
}

// ---------- gather quantized_st + loss sum ----------
__global__ __launch_bounds__(256) void vq_gather_k(
    const float* __restrict__ z, const float* __restrict__ cb,
    const int* __restrict__ idx, float* __restrict__ out,
    float* __restrict__ loss) {
  const int e = blockIdx.x * 256 + threadIdx.x;  // [b][c][hw] flat
  const int hw = e & 1023;
  const int bc = e >> 10;
  const int c = bc & 255;
  const int bimg = bc >> 8;
  const int n = (bimg << 10) + hw;
  const int k = idx[n];
  const float zv = z[e];
  const float q = cb[(size_t)k * 256 + c];
  const float d = q - zv;
  out[e] = zv + d;
  float t = d * d;
  const int lane = threadIdx.x & 63, wid = threadIdx.x >> 6;
  for (int off = 32; off; off >>= 1) t += __shfl_down(t, off);
  __shared__ float ls[4];
  if (lane == 0) ls[wid] = t;
  __syncthreads();
  if (threadIdx.x == 0) atomicAdd(loss, ls[0] + ls[1] + ls[2] + ls[3]);
}

// ---------- perplexity + losses ----------
__global__ __launch_bounds__(256) void vq_final_k(
    const int* __restrict__ hist, const float* __restrict__ loss,
    float* __restrict__ out_tail) {
  float part = 0.f;
  for (int k = threadIdx.x; k < KCB; k += 256) {
    const float p = (float)hist[k] * (1.0f / 16384.0f);
    part += p * logf(fmaxf(p, 1e-10f));
  }
  const int lane = threadIdx.x & 63, wid = threadIdx.x >> 6;
  for (int off = 32; off; off >>= 1) part += __shfl_down(part, off);
  __shared__ float ls[4];
  if (lane == 0) ls[wid] = part;
  __syncthreads();
  if (threadIdx.x == 0) {
    const float s = ls[0] + ls[1] + ls[2] + ls[3];
    out_tail[0] = expf(-s);
    const float mean = *loss * (1.0f / 4194304.0f);
    out_tail[1] = mean;
    out_tail[2] = mean;
  }
}

extern "C" void kernel_launch(void* const* d_in, const int* in_sizes, int n_in,
                              void* d_out, int out_size, void* d_ws,
                              size_t ws_size, hipStream_t stream) {
  const float* z = (const float*)d_in[0];
  const float* cb = (const float*)d_in[1];
  float* out = (float*)d_out;
  char* ws = (char*)d_ws;

  unsigned long long* packed = (unsigned long long*)(ws + OFF_PACKED);
  unsigned short* A = (unsigned short*)(ws + OFF_A);
  unsigned short* B = (unsigned short*)(ws + OFF_B);
  float* nrm = (float*)(ws + OFF_NRM);
  float* pm1 = (float*)(ws + OFF_PM1);
  float* pm2 = (float*)(ws + OFF_PM2);
  int* pidx = (int*)(ws + OFF_PIDX);
  int* prov = (int*)(ws + OFF_PROV);
  int* fidx = (int*)(ws + OFF_FIDX);
  int* flag = (int*)(ws + OFF_FLAG);
  int* list = (int*)(ws + OFF_LIST);
  int* hist = (int*)(ws + OFF_HIST);
  float* loss = (float*)(ws + OFF_LOSS);
  int* cnt = (int*)(ws + OFF_CNT);

  hipMemsetAsync(ws + OFF_HIST, 0, 8192 * 4 + 8, stream);  // hist+loss+cnt

  prep_a_k<<<1024, 256, 0, stream>>>(z, A);
  prep_b_k<<<2048, 256, 0, stream>>>(cb, B, nrm);
  vq_mfma_k<<<dim3(NNB, 128), 256, 0, stream>>>(A, B, nrm, pm1, pm2, pidx);
  reduce1_k<<<64, 256, 0, stream>>>(pm1, pm2, pidx, prov, flag, packed, list, cnt);
  cleanup_k<<<256, 256, 0, stream>>>(z, cb, nrm, list, cnt, packed);
  finalize_k<<<64, 256, 0, stream>>>(prov, flag, packed, fidx, out + 4194304, hist);
  vq_gather_k<<<16384, 256, 0, stream>>>(z, cb, fidx, out, loss);
  vq_final_k<<<1, 256, 0, stream>>>(hist, loss, out + 4210688);
}

// Round 4
// 531.059 us; speedup vs baseline: 37.1085x; 1.3826x over previous
//
#include <hip/hip_runtime.h>
#include <math.h>

typedef __attribute__((ext_vector_type(8))) __bf16 bf16x8;
typedef __attribute__((ext_vector_type(4))) float floatx4;

#define NROW 16384
#define KCB  8192
#define CDIM 256
#define KSPL 768            // [zh|zh|zl] . [eh|el|eh] = zh.eh + zh.el + zl.eh
#define TAU  0.05f          // gap threshold for exact-recompute guard
#define NNB  32             // KCB / 256 n-blocks

// workspace byte offsets
#define OFF_PACKED 0u                    // 16384 * 8
#define OFF_A      131072u               // 16384*768*2 = 25165824
#define OFF_B      25296896u             // 8192*768*2 = 12582912
#define OFF_NRM    37879808u             // 8192*4
#define OFF_PM1    37912576u             // 32*16384*4
#define OFF_PM2    40009728u
#define OFF_PIDX   42106880u
#define OFF_PROV   44204032u             // 16384*4
#define OFF_FIDX   44269568u             // 16384*4
#define OFF_FLAG   44335104u             // 16384*4
#define OFF_LIST   44400640u             // 16384*4
#define OFF_HIST   44466176u             // 8192*4
#define OFF_LOSS   44498944u             // 4
#define OFF_CNT    44498948u             // 4

__device__ __forceinline__ unsigned short f2bf(float f) {  // RNE fp32->bf16 bits
  unsigned u = __float_as_uint(f);
  return (unsigned short)((u + 0x7FFFu + ((u >> 16) & 1u)) >> 16);
}
__device__ __forceinline__ float bf2f(unsigned short b) {
  return __uint_as_float(((unsigned)b) << 16);
}
__device__ __forceinline__ unsigned pack2(unsigned short a, unsigned short b) {
  return (unsigned)a | ((unsigned)b << 16);
}
__device__ __forceinline__ void gld16(const void* g, void* l) {
  __builtin_amdgcn_global_load_lds(
      (const __attribute__((address_space(1))) unsigned int*)g,
      (__attribute__((address_space(3))) unsigned int*)l, 16, 0, 0);
}

// ---------- prep A: z [16,256,32,32] fp32 -> A [16384][768] bf16 ----------
__global__ __launch_bounds__(256) void prep_a_k(const float* __restrict__ z,
                                                unsigned short* __restrict__ A) {
  __shared__ float t[64][65];
  const int tid = threadIdx.x;
  const int bb = blockIdx.x >> 6;
  const int hw0 = ((blockIdx.x >> 2) & 15) * 64;
  const int c0 = (blockIdx.x & 3) * 64;
  const int cl = tid >> 2, h4 = (tid & 3) * 16;
  const float* src = z + ((size_t)(bb * 256 + c0 + cl)) * 1024 + hw0 + h4;
#pragma unroll
  for (int j = 0; j < 4; ++j) {
    const float4 v = *(const float4*)(src + 4 * j);
    t[cl][h4 + 4 * j + 0] = v.x; t[cl][h4 + 4 * j + 1] = v.y;
    t[cl][h4 + 4 * j + 2] = v.z; t[cl][h4 + 4 * j + 3] = v.w;
  }
  __syncthreads();
  const int hl = tid >> 2, cq = (tid & 3) * 16;
  const size_t n = (size_t)bb * 1024 + hw0 + hl;
  unsigned short hi[16], lo[16];
#pragma unroll
  for (int j = 0; j < 16; ++j) {
    const float f = t[cq + j][hl];
    const unsigned short h = f2bf(f);
    hi[j] = h;
    lo[j] = f2bf(f - bf2f(h));
  }
  unsigned short* dst = A + n * 768 + c0 + cq;
  uint4 h0 = {pack2(hi[0], hi[1]), pack2(hi[2], hi[3]), pack2(hi[4], hi[5]), pack2(hi[6], hi[7])};
  uint4 h1 = {pack2(hi[8], hi[9]), pack2(hi[10], hi[11]), pack2(hi[12], hi[13]), pack2(hi[14], hi[15])};
  uint4 l0 = {pack2(lo[0], lo[1]), pack2(lo[2], lo[3]), pack2(lo[4], lo[5]), pack2(lo[6], lo[7])};
  uint4 l1 = {pack2(lo[8], lo[9]), pack2(lo[10], lo[11]), pack2(lo[12], lo[13]), pack2(lo[14], lo[15])};
  *(uint4*)(dst) = h0;        *(uint4*)(dst + 8) = h1;         // zh  seg 0
  *(uint4*)(dst + 256) = h0;  *(uint4*)(dst + 264) = h1;       // zh  seg 1
  *(uint4*)(dst + 512) = l0;  *(uint4*)(dst + 520) = l1;       // zl  seg 2
}

// ---------- prep B: codebook -> B [8192][768] bf16 [eh|el|eh] + norms ----------
__global__ __launch_bounds__(256) void prep_b_k(const float* __restrict__ cb,
                                                unsigned short* __restrict__ B,
                                                float* __restrict__ nrm) {
  const int w = threadIdx.x >> 6, lane = threadIdx.x & 63;
  const int row = blockIdx.x * 4 + w;
  const float4 v = *(const float4*)(cb + (size_t)row * 256 + lane * 4);
  float s = v.x * v.x + v.y * v.y + v.z * v.z + v.w * v.w;
  float f[4] = {v.x, v.y, v.z, v.w};
  ushort4 hv, lv;
  unsigned short* hp = (unsigned short*)&hv;
  unsigned short* lp = (unsigned short*)&lv;
#pragma unroll
  for (int j = 0; j < 4; ++j) {
    const unsigned short h = f2bf(f[j]);
    hp[j] = h;
    lp[j] = f2bf(f[j] - bf2f(h));
  }
  unsigned short* dst = B + (size_t)row * 768 + lane * 4;
  *(ushort4*)(dst) = hv;          // eh
  *(ushort4*)(dst + 256) = lv;    // el
  *(ushort4*)(dst + 512) = hv;    // eh dup
  for (int off = 32; off; off >>= 1) s += __shfl_down(s, off);
  if (lane == 0) nrm[row] = s;
}

// ---------- main: bf16 MFMA distance GEMM + fused top-2 argmin ----------
// block tile 128(M) x 256(N), 4 waves side-by-side in N, wave = 8x4 tiles of
// 16x16x32. LDS octet XOR-swizzle keeps frag reads bank-uniform.
// (proven round 3: 274 us, MfmaUtil 33%, conflicts ~0, absmax 0)
__global__ __launch_bounds__(256, 2) void vq_mfma_k(
    const unsigned short* __restrict__ A, const unsigned short* __restrict__ Bm,
    const float* __restrict__ nrm, float* __restrict__ pm1,
    float* __restrict__ pm2, int* __restrict__ pidx) {
  __shared__ unsigned short As[128 * 64];  // 16 KB
  __shared__ unsigned short Bs[256 * 64];  // 32 KB

  const int tid = threadIdx.x;
  const int mb = blockIdx.y, nb = blockIdx.x;
  const int w = tid >> 6, lane = tid & 63;
  const int quad = lane >> 4, lrow = lane & 15;

  const int sr = tid >> 3, ss = tid & 7;
  const int sq = ss ^ (sr & 7);
  const unsigned short* gA = A + (size_t)(mb * 128 + sr) * 768 + sq * 8;
  const unsigned short* gB = Bm + (size_t)(nb * 256 + sr) * 768 + sq * 8;
  unsigned short* lA = As + sr * 64 + ss * 8;
  unsigned short* lB = Bs + sr * 64 + ss * 8;

  floatx4 acc[8][4];
#pragma unroll
  for (int i = 0; i < 8; ++i)
#pragma unroll
    for (int j = 0; j < 4; ++j) acc[i][j] = (floatx4){0.f, 0.f, 0.f, 0.f};

  for (int kc = 0; kc < 12; ++kc) {
    const int ko = kc * 64;
#pragma unroll
    for (int i = 0; i < 4; ++i)
      gld16(gA + (size_t)(i * 32) * 768 + ko, lA + i * 32 * 64);
#pragma unroll
    for (int i = 0; i < 8; ++i)
      gld16(gB + (size_t)(i * 32) * 768 + ko, lB + i * 32 * 64);
    __syncthreads();
#pragma unroll
    for (int ks = 0; ks < 2; ++ks) {
      bf16x8 af[8], bf[4];
#pragma unroll
      for (int mt = 0; mt < 8; ++mt) {
        const int row = mt * 16 + lrow;
        const int slot = (ks * 4 + quad) ^ (row & 7);
        af[mt] = *(const bf16x8*)(As + row * 64 + slot * 8);
      }
#pragma unroll
      for (int nt = 0; nt < 4; ++nt) {
        const int row = w * 64 + nt * 16 + lrow;
        const int slot = (ks * 4 + quad) ^ (row & 7);
        bf[nt] = *(const bf16x8*)(Bs + row * 64 + slot * 8);
      }
#pragma unroll
      for (int mt = 0; mt < 8; ++mt)
#pragma unroll
        for (int nt = 0; nt < 4; ++nt)
          acc[mt][nt] = __builtin_amdgcn_mfma_f32_16x16x32_bf16(
              af[mt], bf[nt], acc[mt][nt], 0, 0, 0);
    }
    __syncthreads();
  }

  // ---- epilogue: score = nrm[k] - 2*dot; top-2 per row over 256 cols ----
  float nr[4];
#pragma unroll
  for (int nt = 0; nt < 4; ++nt) nr[nt] = nrm[nb * 256 + w * 64 + nt * 16 + lrow];

  float* Lm1 = (float*)As;             // overlay (As dead after loop)
  int* Li1 = (int*)(As + 2048);
  float* Lm2 = (float*)(As + 4096);
#pragma unroll
  for (int mt = 0; mt < 8; ++mt) {
#pragma unroll
    for (int p = 0; p < 4; ++p) {
      float m1 = 3e38f, m2 = 3e38f;
      int i1 = 0;
#pragma unroll
      for (int nt = 0; nt < 4; ++nt) {
        const float s = nr[nt] - 2.0f * acc[mt][nt][p];
        const int kg = nb * 256 + w * 64 + nt * 16 + lrow;
        if (s < m1) { m2 = m1; m1 = s; i1 = kg; }
        else m2 = fminf(m2, s);
      }
      for (int d = 1; d < 16; d <<= 1) {   // merge across 16 lrow lanes
        const float om1 = __shfl_xor(m1, d);
        const int oi1 = __shfl_xor(i1, d);
        const float om2 = __shfl_xor(m2, d);
        if (om1 < m1) { m2 = fminf(m1, om2); m1 = om1; i1 = oi1; }
        else          { m2 = fminf(m2, om1); }
      }
      if (lrow == 0) {
        const int rl = mt * 16 + quad * 4 + p;
        Lm1[rl * 4 + w] = m1; Li1[rl * 4 + w] = i1; Lm2[rl * 4 + w] = m2;
      }
    }
  }
  __syncthreads();
  if (tid < 128) {
    float m1 = Lm1[tid * 4], m2 = Lm2[tid * 4];
    int i1 = Li1[tid * 4];
#pragma unroll
    for (int v = 1; v < 4; ++v) {
      const float om1 = Lm1[tid * 4 + v], om2 = Lm2[tid * 4 + v];
      const int oi1 = Li1[tid * 4 + v];
      if (om1 < m1) { m2 = fminf(m1, om2); m1 = om1; i1 = oi1; }
      else          { m2 = fminf(m2, om1); }
    }
    const int r = mb * 128 + tid;
    pm1[(size_t)nb * NROW + r] = m1;
    pm2[(size_t)nb * NROW + r] = m2;
    pidx[(size_t)nb * NROW + r] = i1;
  }
}

// ---------- reduce partials; flag small-gap rows for exact recompute ----------
__global__ __launch_bounds__(256) void reduce1_k(
    const float* __restrict__ pm1, const float* __restrict__ pm2,
    const int* __restrict__ pidx, int* __restrict__ prov,
    int* __restrict__ flag, unsigned long long* __restrict__ packed,
    int* __restrict__ list, int* __restrict__ cnt) {
  const int r = blockIdx.x * 256 + threadIdx.x;
  float m1 = 3e38f, m2 = 3e38f;
  int i1 = 0;
  for (int nb = 0; nb < NNB; ++nb) {
    const float om1 = pm1[(size_t)nb * NROW + r], om2 = pm2[(size_t)nb * NROW + r];
    const int oi1 = pidx[(size_t)nb * NROW + r];
    if (om1 < m1) { m2 = fminf(m1, om2); m1 = om1; i1 = oi1; }
    else          { m2 = fminf(m2, om1); }
  }
  prov[r] = i1;
  const int fl = (m2 - m1 < TAU) ? 1 : 0;
  flag[r] = fl;
  if (fl) {
    packed[r] = 0xFFFFFFFFFFFFFFFFull;
    const int p = atomicAdd(cnt, 1);
    list[p] = r;
  }
}

// ---------- exact fp32 recompute for flagged rows (parallel over row x k/4) ----
// round-4 change: was a serial loop over flagged rows inside every block
// (~1.5 us/row barrier+latency bound); now each block owns (row, 2048-k
// quarter) and folds via sortable-u64 atomicMin. k ascending in low bits ->
// min picks lowest score, then lowest k (jnp.argmin tie semantics, exact fp32).
__global__ __launch_bounds__(256) void cleanup_k(
    const float* __restrict__ z, const float* __restrict__ cb,
    const float* __restrict__ nrm, const int* __restrict__ list,
    const int* __restrict__ cnt, unsigned long long* __restrict__ packed) {
  __shared__ float zr[256];
  __shared__ unsigned long long red[32];
  const int nf = *cnt;
  const int tid = threadIdx.x;
  const int sub = tid & 7;        // c-octant (32 floats)
  const int kof = tid >> 3;       // 0..31
  const int c0 = sub * 32;
  const int kq = (blockIdx.x & 3) * 2048;     // k-quarter
  for (int f = blockIdx.x >> 2; f < nf; f += 128) {
    const int r = list[f];
    __syncthreads();
    zr[tid] = z[((size_t)((r >> 10) * 256 + tid)) * 1024 + (r & 1023)];
    __syncthreads();
    unsigned long long best = 0xFFFFFFFFFFFFFFFFull;
    for (int it = 0; it < 64; ++it) {
      const int k = kq + it * 32 + kof;
      const float* cr = cb + (size_t)k * 256 + c0;
      float p = 0.f;
#pragma unroll
      for (int c = 0; c < 32; c += 4) {
        const float4 v = *(const float4*)(cr + c);
        p += v.x * zr[c0 + c] + v.y * zr[c0 + c + 1] + v.z * zr[c0 + c + 2] +
             v.w * zr[c0 + c + 3];
      }
      p += __shfl_down(p, 4); p += __shfl_down(p, 2); p += __shfl_down(p, 1);
      if (sub == 0) {
        const float s = nrm[k] - 2.f * p;
        unsigned u = __float_as_uint(s);
        u ^= (unsigned)((int)u >> 31) | 0x80000000u;   // sortable float
        const unsigned long long pk = ((unsigned long long)u << 32) | (unsigned)k;
        best = best < pk ? best : pk;
      }
    }
    if (sub == 0) red[kof] = best;
    __syncthreads();
    if (tid == 0) {
      unsigned long long b = red[0];
#pragma unroll
      for (int i = 1; i < 32; ++i) b = b < red[i] ? b : red[i];
      atomicMin(packed + r, b);
    }
  }
}

// ---------- finalize indices + histogram ----------
__global__ __launch_bounds__(256) void finalize_k(
    const int* __restrict__ prov, const int* __restrict__ flag,
    const unsigned long long* __restrict__ packed, int* __restrict__ fidx,
    float* __restrict__ outf, int* __restrict__ hist) {
  const int r = blockIdx.x * 256 + threadIdx.x;
  const int idx = flag[r] ? (int)(packed[r] & 0xFFFFFFFFull) : prov[r];
  fidx[r] = idx;
  outf[r] = (float)idx;
  atomicAdd(&hist[idx], 1);
}

// ---------- gather quantized_st + loss sum (float4 vectorized) ----------
__global__ __launch_bounds__(256) void vq_gather_k(
    const float* __restrict__ z, const float* __restrict__ cb,
    const int* __restrict__ idx, float* __restrict__ out,
    float* __restrict__ loss) {
  const int e = (blockIdx.x * 256 + threadIdx.x) * 4;  // [b][c][hw] flat, hw%4==0
  const int hw = e & 1023;
  const int bc = e >> 10;
  const int c = bc & 255;
  const int bimg = bc >> 8;
  const int n = (bimg << 10) + hw;
  const int4 k4 = *(const int4*)(idx + n);
  const float4 zv = *(const float4*)(z + e);
  const float q0 = cb[(size_t)k4.x * 256 + c];
  const float q1 = cb[(size_t)k4.y * 256 + c];
  const float q2 = cb[(size_t)k4.z * 256 + c];
  const float q3 = cb[(size_t)k4.w * 256 + c];
  const float d0 = q0 - zv.x, d1 = q1 - zv.y, d2 = q2 - zv.z, d3 = q3 - zv.w;
  float4 ov = {zv.x + d0, zv.y + d1, zv.z + d2, zv.w + d3};  // mirrors z+(q-z)
  *(float4*)(out + e) = ov;
  float t = d0 * d0 + d1 * d1 + d2 * d2 + d3 * d3;
  const int lane = threadIdx.x & 63, wid = threadIdx.x >> 6;
  for (int off = 32; off; off >>= 1) t += __shfl_down(t, off);
  __shared__ float ls[4];
  if (lane == 0) ls[wid] = t;
  __syncthreads();
  if (threadIdx.x == 0) atomicAdd(loss, ls[0] + ls[1] + ls[2] + ls[3]);
}

// ---------- perplexity + losses ----------
__global__ __launch_bounds__(256) void vq_final_k(
    const int* __restrict__ hist, const float* __restrict__ loss,
    float* __restrict__ out_tail) {
  float part = 0.f;
  for (int k = threadIdx.x; k < KCB; k += 256) {
    const float p = (float)hist[k] * (1.0f / 16384.0f);
    part += p * logf(fmaxf(p, 1e-10f));
  }
  const int lane = threadIdx.x & 63, wid = threadIdx.x >> 6;
  for (int off = 32; off; off >>= 1) part += __shfl_down(part, off);
  __shared__ float ls[4];
  if (lane == 0) ls[wid] = part;
  __syncthreads();
  if (threadIdx.x == 0) {
    const float s = ls[0] + ls[1] + ls[2] + ls[3];
    out_tail[0] = expf(-s);
    const float mean = *loss * (1.0f / 4194304.0f);
    out_tail[1] = mean;
    out_tail[2] = mean;
  }
}

extern "C" void kernel_launch(void* const* d_in, const int* in_sizes, int n_in,
                              void* d_out, int out_size, void* d_ws,
                              size_t ws_size, hipStream_t stream) {
  const float* z = (const float*)d_in[0];
  const float* cb = (const float*)d_in[1];
  float* out = (float*)d_out;
  char* ws = (char*)d_ws;

  unsigned long long* packed = (unsigned long long*)(ws + OFF_PACKED);
  unsigned short* A = (unsigned short*)(ws + OFF_A);
  unsigned short* B = (unsigned short*)(ws + OFF_B);
  float* nrm = (float*)(ws + OFF_NRM);
  float* pm1 = (float*)(ws + OFF_PM1);
  float* pm2 = (float*)(ws + OFF_PM2);
  int* pidx = (int*)(ws + OFF_PIDX);
  int* prov = (int*)(ws + OFF_PROV);
  int* fidx = (int*)(ws + OFF_FIDX);
  int* flag = (int*)(ws + OFF_FLAG);
  int* list = (int*)(ws + OFF_LIST);
  int* hist = (int*)(ws + OFF_HIST);
  float* loss = (float*)(ws + OFF_LOSS);
  int* cnt = (int*)(ws + OFF_CNT);

  hipMemsetAsync(ws + OFF_HIST, 0, 8192 * 4 + 8, stream);  // hist+loss+cnt

  prep_a_k<<<1024, 256, 0, stream>>>(z, A);
  prep_b_k<<<2048, 256, 0, stream>>>(cb, B, nrm);
  vq_mfma_k<<<dim3(NNB, 128), 256, 0, stream>>>(A, B, nrm, pm1, pm2, pidx);
  reduce1_k<<<64, 256, 0, stream>>>(pm1, pm2, pidx, prov, flag, packed, list, cnt);
  cleanup_k<<<512, 256, 0, stream>>>(z, cb, nrm, list, cnt, packed);
  finalize_k<<<64, 256, 0, stream>>>(prov, flag, packed, fidx, out + 4194304, hist);
  vq_gather_k<<<4096, 256, 0, stream>>>(z, cb, fidx, out, loss);
  vq_final_k<<<1, 256, 0, stream>>>(hist, loss, out + 4210688);
}